// Round 1
// baseline (407.599 us; speedup 1.0000x reference)
//
#include <hip/hip_runtime.h>
#include <stdint.h>

// Block-sparse linear: out[8192,4096] = x @ W^T + bias, W BSR 64x64 blocks,
// 32 nnz blocks per block-row. Strategy: fp32->bf16 convert into d_ws, then
// MFMA bf16 GEMM per (block-row, M-tile). Threshold (0.107) budgets bf16.

#define BATCH   8192
#define IN_F    4096
#define OUT_F   4096
#define BS      64
#define NROW    64
#define NNZB    2048
#define BM      256                       // batch rows per workgroup
#define LDS_A_BYTES (BM * BS * 2)         // 32768
#define LDS_B_BYTES (BS * BS * 2)         // 8192

typedef float f32x4 __attribute__((ext_vector_type(4)));
typedef short s16x8 __attribute__((ext_vector_type(8)));   // 8 x bf16

__device__ __forceinline__ void async_copy16(const void* g, void* l) {
  // global -> LDS direct DMA, 16 B/lane. LDS side must be base + lane*16.
  __builtin_amdgcn_global_load_lds(
      (__attribute__((address_space(1))) void*)g,
      (__attribute__((address_space(3))) void*)l, 16, 0, 0);
}

__device__ __forceinline__ unsigned short f32_to_bf16(float f) {
  union { float f; uint32_t u; } v; v.f = f;
  // round-to-nearest-even; inputs are finite randoms, no NaN handling needed
  return (unsigned short)((v.u + 0x7FFFu + ((v.u >> 16) & 1u)) >> 16);
}

__global__ void cvt_kernel(const float4* __restrict__ in,
                           ushort4* __restrict__ out, int n4) {
  int i = blockIdx.x * blockDim.x + threadIdx.x;
  if (i < n4) {
    float4 v = in[i];
    ushort4 o;
    o.x = f32_to_bf16(v.x); o.y = f32_to_bf16(v.y);
    o.z = f32_to_bf16(v.z); o.w = f32_to_bf16(v.w);
    out[i] = o;
  }
}

// GEMM: grid (NROW=64, BATCH/BM=32), block 256 = 4 waves.
// Wave w owns rows [w*64, w*64+64) of the 256-row tile x all 64 cols:
// 4x4 grid of 16x16 accumulators (64 VGPRs).
__global__ __launch_bounds__(256) void bsr_gemm_kernel(
    const unsigned short* __restrict__ xb,   // bf16 [BATCH][IN_F]
    const unsigned short* __restrict__ wb,   // bf16 [NNZB][64][64] ([n][k])
    const float* __restrict__ bias,
    const int* __restrict__ crow,
    const int* __restrict__ cols,
    float* __restrict__ out) {
  __shared__ alignas(16) char smem[LDS_A_BYTES + LDS_B_BYTES];

  const int tid = threadIdx.x;
  const int w   = tid >> 6;        // wave 0..3
  const int l   = tid & 63;        // lane
  const int r   = blockIdx.x;      // block-row of W
  const int m0  = blockIdx.y * BM; // batch tile origin

  const int start = crow[r];
  const int end   = crow[r + 1];

  const int lr = l & 15;           // MFMA n/m index within 16
  const int q  = l >> 4;           // quad 0..3

  f32x4 acc[4][4];
#pragma unroll
  for (int mi = 0; mi < 4; ++mi)
#pragma unroll
    for (int ni = 0; ni < 4; ++ni) {
      f32x4 z = {0.f, 0.f, 0.f, 0.f};
      acc[mi][ni] = z;
    }

  // A staging: 8 issues; issue `it` covers tile rows it*32 + w*8 + (l>>3),
  // 16 B per lane => LDS bytes (row*128 + (l&7)*16) == w*1024 + l*16 + it*4096.
  const int arow = (w << 3) + (l >> 3);                       // 0..31
  const unsigned short* agbase =
      xb + (size_t)(m0 + arow) * IN_F + ((l & 7) << 3);       // + c*64 per block
  char* const alds = smem + (w << 10) + (l << 4);             // + it*4096
  // B staging: block is 8192 B contiguous; chunk (it*4+w), lane*16.
  char* const blds = smem + LDS_A_BYTES + (w << 10) + (l << 4); // + it*4096
  const int bgoff = (w << 9) + (l << 3);                      // elements

  for (int i = start; i < end; ++i) {
    const int c = cols[i];                                    // uniform
    const unsigned short* ag = agbase + (size_t)c * BS;
    const unsigned short* bg = wb + ((size_t)i << 12) + bgoff;

    __syncthreads();   // previous compute done before LDS overwrite
#pragma unroll
    for (int it = 0; it < 8; ++it)
      async_copy16(ag + (size_t)(it * 32) * IN_F, alds + it * 4096);
#pragma unroll
    for (int it = 0; it < 2; ++it)
      async_copy16(bg + it * 2048, blds + it * 4096);
    __syncthreads();   // drains vmcnt -> staged data visible

#pragma unroll
    for (int ks = 0; ks < 2; ++ks) {
      s16x8 af[4], bf[4];
#pragma unroll
      for (int mi = 0; mi < 4; ++mi)   // A[m=lr][k=q*8+j], k-block ks*32
        af[mi] = *(const s16x8*)(smem + ((w << 6) + (mi << 4) + lr) * 128 +
                                 (ks << 6) + (q << 4));
#pragma unroll
      for (int ni = 0; ni < 4; ++ni)   // B^T[n=lr][k=q*8+j]
        bf[ni] = *(const s16x8*)(smem + LDS_A_BYTES + ((ni << 4) + lr) * 128 +
                                 (ks << 6) + (q << 4));
#pragma unroll
      for (int mi = 0; mi < 4; ++mi)
#pragma unroll
        for (int ni = 0; ni < 4; ++ni)
          acc[mi][ni] = __builtin_amdgcn_mfma_f32_16x16x32_bf16(
              af[mi], bf[ni], acc[mi][ni], 0, 0, 0);
    }
  }

  // Epilogue: C/D layout col=lr, row=q*4+reg. Add bias, store fp32.
  const int colg = (r << 6) + lr;
#pragma unroll
  for (int ni = 0; ni < 4; ++ni) {
    const float bv = bias[colg + (ni << 4)];
#pragma unroll
    for (int mi = 0; mi < 4; ++mi) {
      float* op = out +
          (size_t)(m0 + (w << 6) + (mi << 4) + (q << 2)) * OUT_F +
          colg + (ni << 4);
#pragma unroll
      for (int e = 0; e < 4; ++e)
        op[(size_t)e * OUT_F] = acc[mi][ni][e] + bv;
    }
  }
}

// Safety net if ws_size < 84 MB: naive fp32, one thread per output element.
__global__ void fallback_kernel(const float* __restrict__ x,
                                const float* __restrict__ vals,
                                const float* __restrict__ bias,
                                const int* __restrict__ crow,
                                const int* __restrict__ cols,
                                float* __restrict__ out) {
  int idx = blockIdx.x * 256 + threadIdx.x;
  int m = idx >> 12;
  int n = idx & 4095;
  int r = n >> 6, nl = n & 63;
  float s = 0.f;
  int e = crow[r + 1];
  for (int i = crow[r]; i < e; ++i) {
    const float* xp = x + (size_t)m * IN_F + cols[i] * 64;
    const float* wp = vals + ((size_t)i << 12) + nl * 64;
    for (int k = 0; k < 64; ++k) s += xp[k] * wp[k];
  }
  out[idx] = s + bias[n];
}

extern "C" void kernel_launch(void* const* d_in, const int* in_sizes, int n_in,
                              void* d_out, int out_size, void* d_ws,
                              size_t ws_size, hipStream_t stream) {
  const float* x    = (const float*)d_in[0];
  const float* vals = (const float*)d_in[1];
  const float* bias = (const float*)d_in[2];
  const int*   crow = (const int*)d_in[3];
  const int*   cols = (const int*)d_in[4];
  float* out = (float*)d_out;

  const size_t x_elems = (size_t)BATCH * IN_F;       // 33.5M
  const size_t w_elems = (size_t)NNZB * BS * BS;     // 8.4M
  const size_t need = (x_elems + w_elems) * 2;       // bf16 bytes, ~84 MB

  if (ws_size >= need) {
    unsigned short* xb = (unsigned short*)d_ws;
    unsigned short* wb = xb + x_elems;
    cvt_kernel<<<(int)(x_elems / 4 / 256), 256, 0, stream>>>(
        (const float4*)x, (ushort4*)xb, (int)(x_elems / 4));
    cvt_kernel<<<(int)(w_elems / 4 / 256), 256, 0, stream>>>(
        (const float4*)vals, (ushort4*)wb, (int)(w_elems / 4));
    dim3 grid(NROW, BATCH / BM);   // r fast => 64 block-rows share an x slab in L2
    bsr_gemm_kernel<<<grid, 256, 0, stream>>>(xb, wb, bias, crow, cols, out);
  } else {
    fallback_kernel<<<(BATCH * OUT_F) / 256, 256, 0, stream>>>(
        x, vals, bias, crow, cols, out);
  }
}